// Round 3
// baseline (139.093 us; speedup 1.0000x reference)
//
#include <hip/hip_runtime.h>
#include <hip/hip_bf16.h>
#include <stdint.h>

typedef __bf16 bf16x8 __attribute__((ext_vector_type(8)));
typedef float  f32x4  __attribute__((ext_vector_type(4)));

#define KC 200
#define KB 10                      // k-components per block
#define CBASE (-58.8120661251f)    // -0.5 * 64 * log(2*pi)

// ws layout:
//   Lt  : bf16 [200][64][64]  ([k][e][d])   bytes        0 .. 1638400
//   muL : f32  [200][64]                    1638400 .. 1689600
//   ck  : f32  [200]                        1689600 .. 1690400

// ---------------- prepass: transpose/convert prec, compute muL + ck ----------------
__global__ __launch_bounds__(256) void prep_b(const float* __restrict__ prec,
                                              const float* __restrict__ means,
                                              __bf16* __restrict__ Lt,
                                              float* __restrict__ muL,
                                              float* __restrict__ ck) {
    __shared__ float sP[64][68];   // [d][e], pad 4 floats
    __shared__ float sM[64];
    const int k = blockIdx.x, tid = threadIdx.x;
    const float* pk = prec + (size_t)k * 4096;
    #pragma unroll
    for (int it = 0; it < 4; ++it) {
        int f4 = tid + it * 256;          // 1024 float4 = 64x64
        float4 v = ((const float4*)pk)[f4];
        int d = f4 >> 4, e0 = (f4 & 15) * 4;
        *(float4*)&sP[d][e0] = v;
    }
    if (tid < 16) *(float4*)&sM[tid * 4] = ((const float4*)(means + (size_t)k * 64))[tid];
    __syncthreads();
    // Lt[k][e][d] = prec[k][d][e], bf16
    #pragma unroll
    for (int it = 0; it < 2; ++it) {
        int c = tid + it * 256;           // 512 chunks of 8
        int e = c >> 3, d0 = (c & 7) * 8;
        bf16x8 o;
        #pragma unroll
        for (int i = 0; i < 8; ++i) o[i] = (__bf16)sP[d0 + i][e];
        *(bf16x8*)(Lt + (size_t)k * 4096 + e * 64 + d0) = o;
    }
    if (tid < 64) {
        int e = tid;
        float m = 0.f;
        #pragma unroll 8
        for (int d = 0; d < 64; ++d) m += sM[d] * sP[d][e];
        muL[k * 64 + e] = m;
        float l = __logf(sP[e][e]);
        #pragma unroll
        for (int mm = 32; mm >= 1; mm >>= 1) l += __shfl_xor(l, mm, 64);
        if (e == 0) ck[k] = l + CBASE;
    }
}

// ---------------- main: swapped-operand fused GEMM + squared-distance ----------------
// C[e][row] = Lt_k . x^T : MFMA A = Lt (m=e), B = x rows (n=row).
// C layout: col(lane&15) = row-in-tile, row(q*4+r) = e-in-tile.
// => ssq reduction over e is per-lane + 2 shuffles (xor16, xor32).
__global__ __launch_bounds__(256, 4) void gmm_main(const float* __restrict__ x,
                                                   const __bf16* __restrict__ Lt,
                                                   const float* __restrict__ muL,
                                                   const float* __restrict__ ck,
                                                   float* __restrict__ out) {
    __shared__ float sOut[256][KB + 1];   // +1 pad: row*11 mod 32 covers all banks

    const int tid  = threadIdx.x;
    const int wave = tid >> 6, lane = tid & 63;
    const int li   = lane & 15, q = lane >> 4;
    const int row0 = blockIdx.x * 256;
    const int rowW = row0 + wave * 64;
    const int k0   = blockIdx.y * KB;

    // --- B-fragments: 64 x-rows per wave, f32 -> bf16 in regs (same addressing R2 validated) ---
    bf16x8 af[4][2];
    #pragma unroll
    for (int tB = 0; tB < 4; ++tB) {
        const float* xr = x + (size_t)(rowW + 16 * tB + li) * 64 + q * 8;
        #pragma unroll
        for (int ks = 0; ks < 2; ++ks) {
            float4 v0 = *(const float4*)(xr + ks * 32);
            float4 v1 = *(const float4*)(xr + ks * 32 + 4);
            bf16x8 a;
            a[0] = (__bf16)v0.x; a[1] = (__bf16)v0.y; a[2] = (__bf16)v0.z; a[3] = (__bf16)v0.w;
            a[4] = (__bf16)v1.x; a[5] = (__bf16)v1.y; a[6] = (__bf16)v1.z; a[7] = (__bf16)v1.w;
            af[tB][ks] = a;
        }
    }

    #pragma unroll 2
    for (int kk = 0; kk < KB; ++kk) {
        const __bf16* Ltk = Lt + (size_t)(k0 + kk) * 4096;
        const float*  muk = muL + (size_t)(k0 + kk) * 64;
        float p[4] = {0.f, 0.f, 0.f, 0.f};

        #pragma unroll
        for (int h = 0; h < 2; ++h) {       // e in two halves of 32 to cap VGPR
            // A-fragments: e-rows 16*(2h+t)+li, d contiguous (L2-resident global)
            bf16x8 lf[2][2];
            #pragma unroll
            for (int t = 0; t < 2; ++t)
                #pragma unroll
                for (int ks = 0; ks < 2; ++ks)
                    lf[t][ks] = *(const bf16x8*)(Ltk + (size_t)(16 * (2 * h + t) + li) * 64
                                                 + ks * 32 + q * 8);
            f32x4 mu0 = *(const f32x4*)(muk + 16 * (2 * h)     + 4 * q);
            f32x4 mu1 = *(const f32x4*)(muk + 16 * (2 * h + 1) + 4 * q);

            f32x4 acc[2][4];
            #pragma unroll
            for (int t = 0; t < 2; ++t)
                #pragma unroll
                for (int tB = 0; tB < 4; ++tB) {
                    acc[t][tB] = __builtin_amdgcn_mfma_f32_16x16x32_bf16(
                        lf[t][0], af[tB][0], (f32x4){0.f, 0.f, 0.f, 0.f}, 0, 0, 0);
                    acc[t][tB] = __builtin_amdgcn_mfma_f32_16x16x32_bf16(
                        lf[t][1], af[tB][1], acc[t][tB], 0, 0, 0);
                }
            #pragma unroll
            for (int tB = 0; tB < 4; ++tB) {
                #pragma unroll
                for (int r = 0; r < 4; ++r) {
                    float z0 = acc[0][tB][r] - mu0[r];
                    float z1 = acc[1][tB][r] - mu1[r];
                    p[tB] = fmaf(z0, z0, p[tB]);
                    p[tB] = fmaf(z1, z1, p[tB]);
                }
            }
        }
        // reduce across the 4 quads (each holds a disjoint e-subset for the same rows)
        #pragma unroll
        for (int tB = 0; tB < 4; ++tB) {
            p[tB] += __shfl_xor(p[tB], 16, 64);
            p[tB] += __shfl_xor(p[tB], 32, 64);
        }
        // lane (q, li) keeps row = 16q + li = lane
        float val = (q == 0) ? p[0] : (q == 1) ? p[1] : (q == 2) ? p[2] : p[3];
        float o   = fmaf(-0.5f, val, ck[k0 + kk]);
        sOut[wave * 64 + lane][kk] = o;
    }
    __syncthreads();

    // --- flush: contiguous KB-float chunks per row ---
    #pragma unroll
    for (int it = 0; it < KB; ++it) {
        int idx = tid + it * 256;             // 0 .. 256*KB-1
        int row = idx / KB, k = idx - row * KB;
        out[(size_t)(row0 + row) * KC + k0 + k] = sOut[row][k];
    }
}

extern "C" void kernel_launch(void* const* d_in, const int* in_sizes, int n_in,
                              void* d_out, int out_size, void* d_ws, size_t ws_size,
                              hipStream_t stream) {
    const float* x     = (const float*)d_in[0];   // [16384, 64]
    const float* means = (const float*)d_in[1];   // [200, 64]
    const float* prec  = (const float*)d_in[2];   // [200, 64, 64]
    float* out = (float*)d_out;                   // [16384, 200]

    __bf16* Lt  = (__bf16*)d_ws;
    float*  muL = (float*)((char*)d_ws + 1638400);
    float*  ckp = (float*)((char*)d_ws + 1689600);

    prep_b<<<200, 256, 0, stream>>>(prec, means, Lt, muL, ckp);
    gmm_main<<<dim3(64, KC / KB), 256, 0, stream>>>(x, Lt, muL, ckp, out);
}

// Round 4
// 97.409 us; speedup vs baseline: 1.4279x; 1.4279x over previous
//
#include <hip/hip_runtime.h>
#include <hip/hip_bf16.h>
#include <stdint.h>

typedef __bf16 bf16x8 __attribute__((ext_vector_type(8)));
typedef float  f32x4  __attribute__((ext_vector_type(4)));

#define KC 200
#define KB 8                       // k-components per block (pow2: shift-only flush)
#define CBASE (-58.8120661251f)    // -0.5 * 64 * log(2*pi)

// ws layout:
//   Lt  : bf16 [200][64][64] ([k][e][d])   bytes        0 .. 1638400
//   muL : f32  [200][64]                   1638400 .. 1689600
//   ckh : f32  [2][200] (partial logdets)  1689600 .. 1691200

// ---------------- prepass: 400 blocks = (k, e-half). transpose+convert, muL, ck halves ----------------
__global__ __launch_bounds__(256) void prep_b(const float* __restrict__ prec,
                                              const float* __restrict__ means,
                                              __bf16* __restrict__ Lt,
                                              float* __restrict__ muL,
                                              float* __restrict__ ckh) {
    __shared__ float sP[64][40];   // [d][e-in-half], padded (160B rows: 16B-aligned)
    __shared__ float sM[64];
    const int k = blockIdx.x >> 1, h = blockIdx.x & 1, tid = threadIdx.x;
    const float* pk = prec + (size_t)k * 4096 + h * 32;
    #pragma unroll
    for (int it = 0; it < 2; ++it) {
        int f4 = tid + it * 256;            // 512 float4 = 64 rows x 8
        int d = f4 >> 3, c = (f4 & 7) * 4;
        float4 v = *(const float4*)(pk + (size_t)d * 64 + c);
        *(float4*)&sP[d][c] = v;
    }
    if (tid < 16) *(float4*)&sM[tid * 4] = ((const float4*)(means + (size_t)k * 64))[tid];
    __syncthreads();
    // Lt[k][h*32+e][d] = prec[k][d][h*32+e], bf16 (256 chunks of 8)
    {
        int e = tid >> 3, d0 = (tid & 7) * 8;
        bf16x8 o;
        #pragma unroll
        for (int i = 0; i < 8; ++i) o[i] = (__bf16)sP[d0 + i][e];
        *(bf16x8*)(Lt + (size_t)k * 4096 + (size_t)(h * 32 + e) * 64 + d0) = o;
    }
    if (tid < 32) {
        int e = tid;
        float m = 0.f;
        #pragma unroll 8
        for (int d = 0; d < 64; ++d) m = fmaf(sM[d], sP[d][e], m);
        muL[k * 64 + h * 32 + e] = m;
        float l = __logf(sP[h * 32 + e][e]);   // diag entry (h*32+e, h*32+e)
        #pragma unroll
        for (int mm = 16; mm >= 1; mm >>= 1) l += __shfl_xor(l, mm, 64);
        if (e == 0) ckh[h * KC + k] = l;
    }
}

// ---------------- main: swapped-operand fused GEMM + squared-distance ----------------
// C[e][row] = Lt_k . x^T - muL (via MFMA C-init). A = Lt (LDS-staged, swizzled), B = x rows (regs).
#define GLL16(gp_, lp_) \
    __builtin_amdgcn_global_load_lds((__attribute__((address_space(1))) const void*)(gp_), \
                                     (__attribute__((address_space(3))) void*)(lp_), 16, 0, 0)

__global__ __launch_bounds__(256, 4) void gmm_main(const float* __restrict__ x,
                                                   const __bf16* __restrict__ Lt,
                                                   const float* __restrict__ muL,
                                                   const float* __restrict__ ckh,
                                                   float* __restrict__ out) {
    __shared__ __align__(16) __bf16 sB[2 * 4096];   // 2 bufs x 8KB, seg-swizzled rows
    __shared__ __align__(16) float  sOut[256][12];  // 8 used + pad to 48B rows
    __shared__ __align__(16) float  sMu[KB * 64];
    __shared__ float sCk[KB];

    const int tid  = threadIdx.x;
    const int wave = tid >> 6, lane = tid & 63;
    const int li   = lane & 15, q = lane >> 4;
    const int r8   = lane >> 3, s8 = lane & 7;
    const int row0 = blockIdx.x * 256;
    const int rowW = row0 + wave * 64;
    const int k0   = blockIdx.y * KB;
    char* sBc = (char*)sB;

    // --- stage Lt_{k0} into buf0 (8 insts across 4 waves; R2-validated swizzle) ---
    {
        const __bf16* L0 = Lt + (size_t)k0 * 4096;
        #pragma unroll
        for (int i = 0; i < 2; ++i) {
            int t = wave * 2 + i;           // 8 rows each
            GLL16(L0 + (size_t)(t * 8 + r8) * 64 + (s8 ^ r8) * 8, sBc + t * 1024);
        }
    }
    if (tid < 128) *(f32x4*)(sMu + tid * 4) = *(const f32x4*)(muL + (size_t)k0 * 64 + tid * 4);
    if (tid < KB)  sCk[tid] = ckh[k0 + tid] + ckh[KC + k0 + tid] + CBASE;

    // --- B-fragments: 64 x-rows per wave, f32 -> bf16 in regs (R2/R3-validated addressing) ---
    bf16x8 af[4][2];
    #pragma unroll
    for (int tB = 0; tB < 4; ++tB) {
        const float* xr = x + (size_t)(rowW + 16 * tB + li) * 64 + q * 8;
        #pragma unroll
        for (int ks = 0; ks < 2; ++ks) {
            float4 v0 = *(const float4*)(xr + ks * 32);
            float4 v1 = *(const float4*)(xr + ks * 32 + 4);
            bf16x8 a;
            a[0] = (__bf16)v0.x; a[1] = (__bf16)v0.y; a[2] = (__bf16)v0.z; a[3] = (__bf16)v0.w;
            a[4] = (__bf16)v1.x; a[5] = (__bf16)v1.y; a[6] = (__bf16)v1.z; a[7] = (__bf16)v1.w;
            af[tB][ks] = a;
        }
    }

    #pragma unroll
    for (int kk = 0; kk < KB; ++kk) {
        __syncthreads();   // buf[kk&1] ready (prefetch had full prior compute phase in flight)
        if (kk + 1 < KB) { // prefetch next k into other buffer (fire-and-forget)
            const __bf16* Ln = Lt + (size_t)(k0 + kk + 1) * 4096;
            char* dst = sBc + ((kk & 1) ^ 1) * 8192;
            #pragma unroll
            for (int i = 0; i < 2; ++i) {
                int t = wave * 2 + i;
                GLL16(Ln + (size_t)(t * 8 + r8) * 64 + (s8 ^ r8) * 8, dst + t * 1024);
            }
        }
        const char* buf = sBc + (kk & 1) * 8192;
        float p[4] = {0.f, 0.f, 0.f, 0.f};

        #pragma unroll
        for (int h = 0; h < 2; ++h) {      // e in two halves of 32 (caps VGPR)
            bf16x8 lf[2][2];
            #pragma unroll
            for (int t = 0; t < 2; ++t) {
                int e = 16 * (2 * h + t) + li;
                #pragma unroll
                for (int ks = 0; ks < 2; ++ks)
                    lf[t][ks] = *(const bf16x8*)(buf + e * 128 + (((ks * 4 + q) ^ (li & 7)) << 4));
            }
            f32x4 acc[2][4];
            #pragma unroll
            for (int t = 0; t < 2; ++t) {
                f32x4 mneg = -*(const f32x4*)(sMu + kk * 64 + 16 * (2 * h + t) + 4 * q);
                #pragma unroll
                for (int tB = 0; tB < 4; ++tB) {
                    acc[t][tB] = __builtin_amdgcn_mfma_f32_16x16x32_bf16(
                        lf[t][0], af[tB][0], mneg, 0, 0, 0);          // C-init = -muL[e]
                    acc[t][tB] = __builtin_amdgcn_mfma_f32_16x16x32_bf16(
                        lf[t][1], af[tB][1], acc[t][tB], 0, 0, 0);
                }
            }
            #pragma unroll
            for (int tB = 0; tB < 4; ++tB)
                #pragma unroll
                for (int t = 0; t < 2; ++t)
                    #pragma unroll
                    for (int r = 0; r < 4; ++r)
                        p[tB] = fmaf(acc[t][tB][r], acc[t][tB][r], p[tB]);
        }
        // sum across quads (each quad holds a disjoint e-subset for the same rows)
        #pragma unroll
        for (int tB = 0; tB < 4; ++tB) {
            p[tB] += __shfl_xor(p[tB], 16, 64);
            p[tB] += __shfl_xor(p[tB], 32, 64);
        }
        float val = (q == 0) ? p[0] : (q == 1) ? p[1] : (q == 2) ? p[2] : p[3];
        sOut[wave * 64 + lane][kk] = fmaf(-0.5f, val, sCk[kk]);   // row = lane within wave-tile
    }
    __syncthreads();

    // --- flush: one row (8 contiguous k) per thread, two float4 stores ---
    {
        f32x4 a = *(const f32x4*)&sOut[tid][0];
        f32x4 b = *(const f32x4*)&sOut[tid][4];
        float* op = out + (size_t)(row0 + tid) * KC + k0;
        *(f32x4*)op = a;
        *(f32x4*)(op + 4) = b;
    }
}

extern "C" void kernel_launch(void* const* d_in, const int* in_sizes, int n_in,
                              void* d_out, int out_size, void* d_ws, size_t ws_size,
                              hipStream_t stream) {
    const float* x     = (const float*)d_in[0];   // [16384, 64]
    const float* means = (const float*)d_in[1];   // [200, 64]
    const float* prec  = (const float*)d_in[2];   // [200, 64, 64]
    float* out = (float*)d_out;                   // [16384, 200]

    __bf16* Lt  = (__bf16*)d_ws;
    float*  muL = (float*)((char*)d_ws + 1638400);
    float*  ckh = (float*)((char*)d_ws + 1689600);

    prep_b<<<400, 256, 0, stream>>>(prec, means, Lt, muL, ckh);
    gmm_main<<<dim3(64, KC / KB), 256, 0, stream>>>(x, Lt, muL, ckh, out);
}